// Round 4
// baseline (379.025 us; speedup 1.0000x reference)
//
#include <hip/hip_runtime.h>
#include <cstdint>
#include <cstddef>

#define AS1 __attribute__((address_space(1)))
#define AS3 __attribute__((address_space(3)))

typedef unsigned int u32;
typedef unsigned char u8;
typedef int i32x4 __attribute__((ext_vector_type(4)));
typedef int i32x8 __attribute__((ext_vector_type(8)));
typedef float f32x4 __attribute__((ext_vector_type(4)));

constexpr int D  = 1024;   // K
constexpr int NS = 16384;  // rows of x (M)
constexpr int US = 4096;   // rows of w (N of output)
constexpr int BM = 256, BN = 256, BK = 128;  // BK in fp8 elements (= bytes)
constexpr int KT = D / BK;                   // 8 K-tiles

// ws layout: xq 16MB | wq 4MB | xsq 64KB | wsq 16KB
constexpr size_t XQ_OFF  = 0;
constexpr size_t WQ_OFF  = (size_t)NS * D;
constexpr size_t XSQ_OFF = WQ_OFF + (size_t)US * D;
constexpr size_t WSQ_OFF = XSQ_OFF + (size_t)NS * 4;

// Fused prepass: one wave per row (grid-stride), no barriers.
__global__ __launch_bounds__(256) void quant_sq(
    const float* __restrict__ x, const float* __restrict__ w,
    u8* __restrict__ xq, u8* __restrict__ wq,
    float* __restrict__ xsq, float* __restrict__ wsq) {
  const int lane = threadIdx.x & 63;
  const int wave = blockIdx.x * 4 + (threadIdx.x >> 6);
  const int nwaves = gridDim.x * 4;
  for (int row = wave; row < NS + US; row += nwaves) {
    const float* src; u8* qdst; float* sdst; int r; float qscale;
    if (row < NS) { src = x; qdst = xq; sdst = xsq; r = row; qscale = 1.0f; }
    else          { src = w; qdst = wq; sdst = wsq; r = row - NS; qscale = 16.0f; }
    const float4* s4 = (const float4*)(src + (size_t)r * D);
    u32* qrow = (u32*)(qdst + (size_t)r * D);
    float s = 0.f;
#pragma unroll
    for (int it = 0; it < 4; ++it) {
      const float4 v = s4[it * 64 + lane];
      s += v.x * v.x + v.y * v.y + v.z * v.z + v.w * v.w;
      u32 p01 = __builtin_amdgcn_cvt_pk_fp8_f32(v.x * qscale, v.y * qscale, 0, false);
      u32 w0  = __builtin_amdgcn_cvt_pk_fp8_f32(v.z * qscale, v.w * qscale, p01, true);
      qrow[it * 64 + lane] = w0;
    }
#pragma unroll
    for (int off = 32; off; off >>= 1) s += __shfl_down(s, off, 64);
    if (lane == 0) sdst[r] = s;
  }
}

// out[R][C] = xsq[R] + wsq[C] - 0.125 * sum_k e4m3(x)[R][k] * e4m3(16w)[C][k]
// 256x256 tile, 8 waves (2M x 4N), per-wave output 128x64.
// One barrier per phase; A-fragments pre-read one phase ahead (latency hidden
// under MFMAs); stages issued inside MFMA windows; vmcnt drained BEFORE the
// barrier that publishes the staged buffer (per-wave vmcnt + barrier = all
// waves' DMA visible). Only B's 8 ds_reads/tile are latency-exposed.
__global__ __launch_bounds__(512, 2) void dist_gemm(
    const u8* __restrict__ xq, const u8* __restrict__ wq,
    const float* __restrict__ xsq, const float* __restrict__ wsq,
    float* __restrict__ out) {
  __shared__ u8 lds[2 * 65536];  // per buf: A 32KB (256 rows x 128B) | B 32KB

  const int tid = threadIdx.x;
  const int lane = tid & 63;
  const int wv = tid >> 6;      // wave 0..7
  const int wm = wv >> 2;       // 0..1  (128-row half of BM)
  const int wn = wv & 3;        // 0..3  (64-col quarter of BN)
  const int quad = lane >> 4;
  const int l15 = lane & 15;

  const int m0 = blockIdx.y * BM;
  const int n0 = blockIdx.x * BN;

  const int srow = tid >> 3;    // row 0..63 within a 64-row staging sweep
  const int sch = lane & 7;     // 16B chunk within the 128B row

  f32x4 acc[8][4];
#pragma unroll
  for (int mt = 0; mt < 8; ++mt)
#pragma unroll
    for (int nt = 0; nt < 4; ++nt) acc[mt][nt] = (f32x4){0.f, 0.f, 0.f, 0.f};

  auto stageA = [&](int buf, int kt, int sw) {
    const int r = sw * 64 + srow;
    const int cg = sch ^ (r & 7);   // XOR-swizzle applied on GLOBAL side
    const u8* g = xq + (size_t)(m0 + r) * D + kt * BK + cg * 16;
    __builtin_amdgcn_global_load_lds((AS1 void*)(u8*)g,
        (AS3 void*)(lds + buf * 65536 + sw * 8192 + wv * 1024), 16, 0, 0);
  };
  auto stageB = [&](int buf, int kt, int sw) {
    const int r = sw * 64 + srow;
    const int cg = sch ^ (r & 7);
    const u8* g = wq + (size_t)(n0 + r) * D + kt * BK + cg * 16;
    __builtin_amdgcn_global_load_lds((AS1 void*)(u8*)g,
        (AS3 void*)(lds + buf * 65536 + 32768 + sw * 8192 + wv * 1024), 16, 0, 0);
  };
  auto ldfrag = [&](const u8* mat, int row) -> i32x8 {
    const int s = row & 7;
    const i32x4 f0 = *reinterpret_cast<const i32x4*>(mat + row * BK + ((2 * quad) ^ s) * 16);
    const i32x4 f1 = *reinterpret_cast<const i32x4*>(mat + row * BK + ((2 * quad + 1) ^ s) * 16);
    return __builtin_shufflevector(f0, f1, 0, 1, 2, 3, 4, 5, 6, 7);
  };

  const int ar = wm * 128 + l15;
  const int br = wn * 64 + l15;

  // ---- prologue: stage tiles 0 and 1 fully; drain tile 0 (own loads), then
  //      the phase-0 barrier publishes all waves' tile-0 data ----
#pragma unroll
  for (int sw = 0; sw < 4; ++sw) stageA(0, 0, sw);
#pragma unroll
  for (int sw = 0; sw < 4; ++sw) stageB(0, 0, sw);
#pragma unroll
  for (int sw = 0; sw < 4; ++sw) stageA(1, 1, sw);
#pragma unroll
  for (int sw = 0; sw < 4; ++sw) stageB(1, 1, sw);
  asm volatile("s_waitcnt vmcnt(8)" ::: "memory");
  __builtin_amdgcn_sched_barrier(0);

#define MM(MT, NT, AF) \
  acc[MT][NT] = __builtin_amdgcn_mfma_scale_f32_16x16x128_f8f6f4( \
      AF, bf[NT], acc[MT][NT], 0, 0, 0, 0x7F7F7F7F, 0, 0x7F7F7F7F)

#define SB() __builtin_amdgcn_sched_barrier(0)

  i32x8 a00, a01;  // current phase-0 A pair, pre-read one tile ahead

#pragma unroll
  for (int t = 0; t < KT - 1; ++t) {
    const u8* sA = lds + (t & 1) * 65536;
    const u8* sB = sA + 32768;
    const int nb = (t + 1) & 1;
    const u8* nA = lds + nb * 65536;
    const int cur = t & 1;

    i32x8 bf[4];

    // ===== phase 0: B reads (exposed once/tile) + MFMA mt{0,1} =====
    __builtin_amdgcn_s_barrier();
    SB();
    bf[0] = ldfrag(sB, br);
    bf[1] = ldfrag(sB, br + 16);
    bf[2] = ldfrag(sB, br + 32);
    bf[3] = ldfrag(sB, br + 48);
    if (t == 0) { a00 = ldfrag(sA, ar); a01 = ldfrag(sA, ar + 16); }
    asm volatile("s_waitcnt lgkmcnt(0)" ::: "memory");
    SB();
    __builtin_amdgcn_s_setprio(1);
    if (t >= 1) { stageA(nb, t + 1, 1); stageA(nb, t + 1, 3); }
    i32x8 a02 = ldfrag(sA, ar + 32);
    i32x8 a03 = ldfrag(sA, ar + 48);
    SB();
    MM(0, 0, a00); MM(0, 1, a00); MM(0, 2, a00); MM(0, 3, a00);
    MM(1, 0, a01); MM(1, 1, a01); MM(1, 2, a01); MM(1, 3, a01);
    __builtin_amdgcn_s_setprio(0);
    SB();

    // ===== phase 1: MFMA mt{2,3}; pre-read mt{4,5}; stage B(t+2) =====
    __builtin_amdgcn_s_barrier();
    SB();
    asm volatile("s_waitcnt lgkmcnt(0)" ::: "memory");
    SB();
    __builtin_amdgcn_s_setprio(1);
    if (t + 2 < KT) { stageB(cur, t + 2, 0); stageB(cur, t + 2, 1); stageB(cur, t + 2, 2); }
    i32x8 a04 = ldfrag(sA, ar + 64);
    i32x8 a05 = ldfrag(sA, ar + 80);
    SB();
    MM(2, 0, a02); MM(2, 1, a02); MM(2, 2, a02); MM(2, 3, a02);
    MM(3, 0, a03); MM(3, 1, a03); MM(3, 2, a03); MM(3, 3, a03);
    __builtin_amdgcn_s_setprio(0);
    SB();

    // ===== phase 2: MFMA mt{4,5}; pre-read mt{6,7}; stage B3,A0,A2(t+2);
    //        then drain t+1's loads BEFORE phase-3's barrier =====
    __builtin_amdgcn_s_barrier();
    SB();
    asm volatile("s_waitcnt lgkmcnt(0)" ::: "memory");
    SB();
    __builtin_amdgcn_s_setprio(1);
    if (t + 2 < KT) { stageB(cur, t + 2, 3); stageA(cur, t + 2, 0); stageA(cur, t + 2, 2); }
    i32x8 a06 = ldfrag(sA, ar + 96);
    i32x8 a07 = ldfrag(sA, ar + 112);
    SB();
    MM(4, 0, a04); MM(4, 1, a04); MM(4, 2, a04); MM(4, 3, a04);
    MM(5, 0, a05); MM(5, 1, a05); MM(5, 2, a05); MM(5, 3, a05);
    __builtin_amdgcn_s_setprio(0);
    SB();
    if (t < KT - 2) asm volatile("s_waitcnt vmcnt(6)" ::: "memory");
    else            asm volatile("s_waitcnt vmcnt(2)" ::: "memory");
    SB();

    // ===== phase 3: MFMA mt{6,7}; pre-read NEXT tile's mt{0,1} =====
    __builtin_amdgcn_s_barrier();
    SB();
    asm volatile("s_waitcnt lgkmcnt(0)" ::: "memory");
    SB();
    __builtin_amdgcn_s_setprio(1);
    a00 = ldfrag(nA, ar);
    a01 = ldfrag(nA, ar + 16);
    SB();
    MM(6, 0, a06); MM(6, 1, a06); MM(6, 2, a06); MM(6, 3, a06);
    MM(7, 0, a07); MM(7, 1, a07); MM(7, 2, a07); MM(7, 3, a07);
    __builtin_amdgcn_s_setprio(0);
    SB();
  }

  // drain tile-7's last two DMA loads (A1,A3), publish, then barrier-free tail
  asm volatile("s_waitcnt vmcnt(0)" ::: "memory");
  SB();
  __builtin_amdgcn_s_barrier();
  SB();

  // ---- peeled tile 7 (buffer 1): no staging in flight; epilogue loads and
  //      stores interleaved under the final MFMA clusters ----
  {
    const u8* sA = lds + 65536;
    const u8* sB = sA + 32768;

    float wsv[4];
#pragma unroll
    for (int nt = 0; nt < 4; ++nt) wsv[nt] = wsq[n0 + wn * 64 + nt * 16 + l15];

    i32x8 bf[4];
    bf[0] = ldfrag(sB, br);
    bf[1] = ldfrag(sB, br + 16);
    bf[2] = ldfrag(sB, br + 32);
    bf[3] = ldfrag(sB, br + 48);

    auto xs_of = [&](int mt) -> f32x4 {
      return *reinterpret_cast<const f32x4*>(xsq + m0 + wm * 128 + mt * 16 + quad * 4);
    };
    auto store2 = [&](int mt, const f32x4 xs) {
      const int R0 = m0 + wm * 128 + mt * 16 + quad * 4;
#pragma unroll
      for (int nt = 0; nt < 4; ++nt) {
        const int C = n0 + wn * 64 + nt * 16 + l15;
#pragma unroll
        for (int r = 0; r < 4; ++r)
          out[(size_t)(R0 + r) * US + C] = xs[r] + wsv[nt] - 0.125f * acc[mt][nt][r];
      }
    };

    f32x4 xs0 = xs_of(0), xs1 = xs_of(1);
    {
      __builtin_amdgcn_s_setprio(1);
      MM(0, 0, a00); MM(0, 1, a00); MM(0, 2, a00); MM(0, 3, a00);
      MM(1, 0, a01); MM(1, 1, a01); MM(1, 2, a01); MM(1, 3, a01);
      __builtin_amdgcn_s_setprio(0);
    }
    f32x4 xs2 = xs_of(2), xs3 = xs_of(3);
    {
      i32x8 a0 = ldfrag(sA, ar + 32);
      i32x8 a1 = ldfrag(sA, ar + 48);
      __builtin_amdgcn_s_setprio(1);
      MM(2, 0, a0); MM(2, 1, a0); MM(2, 2, a0); MM(2, 3, a0);
      MM(3, 0, a1); MM(3, 1, a1); MM(3, 2, a1); MM(3, 3, a1);
      __builtin_amdgcn_s_setprio(0);
    }
    store2(0, xs0); store2(1, xs1);
    f32x4 xs4 = xs_of(4), xs5 = xs_of(5);
    {
      i32x8 a0 = ldfrag(sA, ar + 64);
      i32x8 a1 = ldfrag(sA, ar + 80);
      __builtin_amdgcn_s_setprio(1);
      MM(4, 0, a0); MM(4, 1, a0); MM(4, 2, a0); MM(4, 3, a0);
      MM(5, 0, a1); MM(5, 1, a1); MM(5, 2, a1); MM(5, 3, a1);
      __builtin_amdgcn_s_setprio(0);
    }
    store2(2, xs2); store2(3, xs3);
    f32x4 xs6 = xs_of(6), xs7 = xs_of(7);
    {
      i32x8 a0 = ldfrag(sA, ar + 96);
      i32x8 a1 = ldfrag(sA, ar + 112);
      __builtin_amdgcn_s_setprio(1);
      MM(6, 0, a0); MM(6, 1, a0); MM(6, 2, a0); MM(6, 3, a0);
      MM(7, 0, a1); MM(7, 1, a1); MM(7, 2, a1); MM(7, 3, a1);
      __builtin_amdgcn_s_setprio(0);
    }
    store2(4, xs4); store2(5, xs5);
    store2(6, xs6); store2(7, xs7);
  }
}

extern "C" void kernel_launch(void* const* d_in, const int* in_sizes, int n_in,
                              void* d_out, int out_size, void* d_ws, size_t ws_size,
                              hipStream_t stream) {
  const float* x = (const float*)d_in[0];  // [16384, 1024]
  const float* w = (const float*)d_in[1];  // [4096, 1024]
  float* out = (float*)d_out;              // [16384, 4096]
  char* ws = (char*)d_ws;                  // ~20.1 MB used

  u8* xq = (u8*)(ws + XQ_OFF);
  u8* wq = (u8*)(ws + WQ_OFF);
  float* xsq = (float*)(ws + XSQ_OFF);
  float* wsq = (float*)(ws + WSQ_OFF);

  quant_sq<<<dim3(1280), dim3(256), 0, stream>>>(x, w, xq, wq, xsq, wsq);
  dist_gemm<<<dim3(US / BN, NS / BM), dim3(512), 0, stream>>>(xq, wq, xsq, wsq, out);
}

// Round 5
// 373.185 us; speedup vs baseline: 1.0156x; 1.0156x over previous
//
#include <hip/hip_runtime.h>
#include <cstdint>
#include <cstddef>

#define AS1 __attribute__((address_space(1)))
#define AS3 __attribute__((address_space(3)))

typedef unsigned int u32;
typedef unsigned char u8;
typedef int i32x4 __attribute__((ext_vector_type(4)));
typedef int i32x8 __attribute__((ext_vector_type(8)));
typedef float f32x4 __attribute__((ext_vector_type(4)));

constexpr int D  = 1024;   // K
constexpr int NS = 16384;  // rows of x (M)
constexpr int US = 4096;   // rows of w (N of output)
constexpr int BM = 128, BN = 128, BK = 128;  // BK in fp8 elements (= bytes)
constexpr int KT = D / BK;                   // 8 K-tiles

// ws layout: xq 16MB | wq 4MB | xsq 64KB | wsq 16KB
constexpr size_t XQ_OFF  = 0;
constexpr size_t WQ_OFF  = (size_t)NS * D;
constexpr size_t XSQ_OFF = WQ_OFF + (size_t)US * D;
constexpr size_t WSQ_OFF = XSQ_OFF + (size_t)NS * 4;

// Fused prepass: one wave per row (grid-stride), no barriers.
__global__ __launch_bounds__(256) void quant_sq(
    const float* __restrict__ x, const float* __restrict__ w,
    u8* __restrict__ xq, u8* __restrict__ wq,
    float* __restrict__ xsq, float* __restrict__ wsq) {
  const int lane = threadIdx.x & 63;
  const int wave = blockIdx.x * 4 + (threadIdx.x >> 6);
  const int nwaves = gridDim.x * 4;
  for (int row = wave; row < NS + US; row += nwaves) {
    const float* src; u8* qdst; float* sdst; int r; float qscale;
    if (row < NS) { src = x; qdst = xq; sdst = xsq; r = row; qscale = 1.0f; }
    else          { src = w; qdst = wq; sdst = wsq; r = row - NS; qscale = 16.0f; }
    const float4* s4 = (const float4*)(src + (size_t)r * D);
    u32* qrow = (u32*)(qdst + (size_t)r * D);
    float s = 0.f;
#pragma unroll
    for (int it = 0; it < 4; ++it) {
      const float4 v = s4[it * 64 + lane];
      s += v.x * v.x + v.y * v.y + v.z * v.z + v.w * v.w;
      u32 p01 = __builtin_amdgcn_cvt_pk_fp8_f32(v.x * qscale, v.y * qscale, 0, false);
      u32 w0  = __builtin_amdgcn_cvt_pk_fp8_f32(v.z * qscale, v.w * qscale, p01, true);
      qrow[it * 64 + lane] = w0;
    }
#pragma unroll
    for (int off = 32; off; off >>= 1) s += __shfl_down(s, off, 64);
    if (lane == 0) sdst[r] = s;
  }
}

// out[R][C] = xsq[R] + wsq[C] - 0.125 * sum_k e4m3(x)[R][k] * e4m3(16w)[C][k]
// 128x128 tile, 4 waves (2M x 2N), per-wave output 64x64.
// LDS = 2 x (A 16KB | B 16KB) = 64 KB -> 2 blocks/CU co-resident: two
// independent barrier domains overlap LDS-read bursts with MFMA bursts
// (the 256^2/128KB version was 1 block/CU and serialized; m132 regression).
// T3-minimum loop: stage(t+1) issued BEFORE ds_reads(t); lgkmcnt(0) -> 16
// MFMA; one vmcnt(0)+barrier per tile (stage latency hides under compute).
__global__ __launch_bounds__(256, 2) void dist_gemm(
    const u8* __restrict__ xq, const u8* __restrict__ wq,
    const float* __restrict__ xsq, const float* __restrict__ wsq,
    float* __restrict__ out) {
  __shared__ u8 lds[2 * 32768];

  const int tid = threadIdx.x;
  const int lane = tid & 63;
  const int wv = tid >> 6;      // wave 0..3
  const int wm = wv >> 1;       // 0..1  (64-row half of BM)
  const int wn = wv & 1;        // 0..1  (64-col half of BN)
  const int quad = lane >> 4;
  const int l15 = lane & 15;

  const int m0 = blockIdx.y * BM;
  const int n0 = blockIdx.x * BN;

  const int srow = tid >> 3;    // row 0..31 within a 32-row staging sweep
  const int sch = lane & 7;     // 16B chunk within the 128B row

  f32x4 acc[4][4];
#pragma unroll
  for (int mt = 0; mt < 4; ++mt)
#pragma unroll
    for (int nt = 0; nt < 4; ++nt) acc[mt][nt] = (f32x4){0.f, 0.f, 0.f, 0.f};

  // one global_load_lds per thread per sweep: 256 thr x 16B = 4KB = 32 rows
  auto stageA = [&](int buf, int kt, int sw) {
    const int r = sw * 32 + srow;
    const int cg = sch ^ (r & 7);   // XOR-swizzle applied on GLOBAL side
    const u8* g = xq + (size_t)(m0 + r) * D + kt * BK + cg * 16;
    __builtin_amdgcn_global_load_lds((AS1 void*)(u8*)g,
        (AS3 void*)(lds + buf * 32768 + sw * 4096 + wv * 1024), 16, 0, 0);
  };
  auto stageB = [&](int buf, int kt, int sw) {
    const int r = sw * 32 + srow;
    const int cg = sch ^ (r & 7);
    const u8* g = wq + (size_t)(n0 + r) * D + kt * BK + cg * 16;
    __builtin_amdgcn_global_load_lds((AS1 void*)(u8*)g,
        (AS3 void*)(lds + buf * 32768 + 16384 + sw * 4096 + wv * 1024), 16, 0, 0);
  };
  auto ldfrag = [&](const u8* mat, int row) -> i32x8 {
    const int s = row & 7;
    const i32x4 f0 = *reinterpret_cast<const i32x4*>(mat + row * BK + ((2 * quad) ^ s) * 16);
    const i32x4 f1 = *reinterpret_cast<const i32x4*>(mat + row * BK + ((2 * quad + 1) ^ s) * 16);
    return __builtin_shufflevector(f0, f1, 0, 1, 2, 3, 4, 5, 6, 7);
  };

  const int ar = wm * 64 + l15;
  const int br = wn * 64 + l15;

#define MM(MT, NT, AF) \
  acc[MT][NT] = __builtin_amdgcn_mfma_scale_f32_16x16x128_f8f6f4( \
      AF, bf[NT], acc[MT][NT], 0, 0, 0, 0x7F7F7F7F, 0, 0x7F7F7F7F)

#define SB() __builtin_amdgcn_sched_barrier(0)

  // ---- prologue: stage tile 0, drain, publish ----
#pragma unroll
  for (int sw = 0; sw < 4; ++sw) stageA(0, 0, sw);
#pragma unroll
  for (int sw = 0; sw < 4; ++sw) stageB(0, 0, sw);
  asm volatile("s_waitcnt vmcnt(0)" ::: "memory");
  SB();
  __builtin_amdgcn_s_barrier();
  SB();

#pragma unroll
  for (int t = 0; t < KT; ++t) {
    const u8* sA = lds + (t & 1) * 32768;
    const u8* sB = sA + 16384;
    const int nb = (t + 1) & 1;

    // issue next tile's staging FIRST (latency hides under reads + MFMAs)
    if (t + 1 < KT) {
#pragma unroll
      for (int sw = 0; sw < 4; ++sw) stageA(nb, t + 1, sw);
#pragma unroll
      for (int sw = 0; sw < 4; ++sw) stageB(nb, t + 1, sw);
    }

    i32x8 bf[4];
    bf[0] = ldfrag(sB, br);
    bf[1] = ldfrag(sB, br + 16);
    bf[2] = ldfrag(sB, br + 32);
    bf[3] = ldfrag(sB, br + 48);
    i32x8 a0 = ldfrag(sA, ar);
    i32x8 a1 = ldfrag(sA, ar + 16);
    i32x8 a2 = ldfrag(sA, ar + 32);
    i32x8 a3 = ldfrag(sA, ar + 48);

    asm volatile("s_waitcnt lgkmcnt(0)" ::: "memory");
    SB();
    __builtin_amdgcn_s_setprio(1);
    MM(0, 0, a0); MM(0, 1, a0); MM(0, 2, a0); MM(0, 3, a0);
    MM(1, 0, a1); MM(1, 1, a1); MM(1, 2, a1); MM(1, 3, a1);
    MM(2, 0, a2); MM(2, 1, a2); MM(2, 2, a2); MM(2, 3, a2);
    MM(3, 0, a3); MM(3, 1, a3); MM(3, 2, a3); MM(3, 3, a3);
    __builtin_amdgcn_s_setprio(0);
    SB();

    if (t + 1 < KT) {
      // own 8 staging loads done -> barrier publishes all waves' DMA
      asm volatile("s_waitcnt vmcnt(0)" ::: "memory");
      SB();
      __builtin_amdgcn_s_barrier();
      SB();
    }
  }

  // ---- epilogue: C/D layout col = lane&15 (n), row = quad*4 + reg (m) ----
  float wsv[4];
#pragma unroll
  for (int nt = 0; nt < 4; ++nt) wsv[nt] = wsq[n0 + wn * 64 + nt * 16 + l15];

#pragma unroll
  for (int mt = 0; mt < 4; ++mt) {
    const int R0 = m0 + wm * 64 + mt * 16 + quad * 4;
    const f32x4 xs = *reinterpret_cast<const f32x4*>(xsq + R0);
#pragma unroll
    for (int nt = 0; nt < 4; ++nt) {
      const int C = n0 + wn * 64 + nt * 16 + l15;
#pragma unroll
      for (int r = 0; r < 4; ++r)
        out[(size_t)(R0 + r) * US + C] = xs[r] + wsv[nt] - 0.125f * acc[mt][nt][r];
    }
  }
}

extern "C" void kernel_launch(void* const* d_in, const int* in_sizes, int n_in,
                              void* d_out, int out_size, void* d_ws, size_t ws_size,
                              hipStream_t stream) {
  const float* x = (const float*)d_in[0];  // [16384, 1024]
  const float* w = (const float*)d_in[1];  // [4096, 1024]
  float* out = (float*)d_out;              // [16384, 4096]
  char* ws = (char*)d_ws;                  // ~20.1 MB used

  u8* xq = (u8*)(ws + XQ_OFF);
  u8* wq = (u8*)(ws + WQ_OFF);
  float* xsq = (float*)(ws + XSQ_OFF);
  float* wsq = (float*)(ws + WSQ_OFF);

  quant_sq<<<dim3(1280), dim3(256), 0, stream>>>(x, w, xq, wq, xsq, wsq);
  dist_gemm<<<dim3(US / BN, NS / BM), dim3(256), 0, stream>>>(xq, wq, xsq, wsq, out);
}